// Round 15
// baseline (61.667 us; speedup 1.0000x reference)
//
#include <hip/hip_runtime.h>

#define DIM 1024
#define ROWS_PER_TILE 16

typedef float  f32x4  __attribute__((ext_vector_type(4)));
typedef short  bf16x8 __attribute__((ext_vector_type(8)));
typedef unsigned int u32x4 __attribute__((ext_vector_type(4)));

#define WF_BYTES (2 * 32 * 2 * 64 * 16)   // wf1 (64KB) + wf2 (64KB) in d_ws

// ===========================================================================
// y = x * M. Stages 0-4 -> blockdiag A_g (contiguous 32-groups g);
// stages 5-9 -> blockdiag B_t (stride-32 groups t).
// r15: ONE WAVE PER BLOCK (64 thr), 16 rows/wave, grid=1024 -> exactly 4
// blocks/CU; ENTIRE GRID RESIDENT at t=0 (fix for the session-long ~43us
// plateau: phase-serial 256-thr blocks left HBM idle during compute; fill
// kernel proves 6.7 TB/s is available).
// Layer 1 (swapped, r14-verified): mfma(wf1frag, xfrag) -> lane (q,lr) holds
//   z[x-row=lr][c=nh*16+q*4+i] for group g; 8-g chunks -> b128 zt writes.
// zt unit U = c*64 + lr*4 + gc, swz U ^= (U>>8)&3  (write: q->bits01 via c;
//   read U = t*64+lr*4+q: q->bits01 directly; both 2-way-free).
// Layer 2 (swapped, r14-verified): mfma(wf2frag, zfrag) -> lane (q,lr) holds
//   y[row=lr][(nh*16+q*4+i)*32 + t]; t-loop accumulates y[2][4][8] f32x4
//   (lane owns 32 CONSECUTIVE cols per (nh,i)).
// y re-staged bf16 in zt: unit V = lr*128 + c*4 + tc, swz V ^= (V>>7)&7.
// Final stores: lane l -> row l>>2, 32B each; per INSTRUCTION 4 lanes cover a
// dense 128B line x 16 rows (r11 evidence: partial-line stores double WRITE).
// Barriers are 1-wave (cheap); all cross-lane traffic is wave-private LDS.
// NOTE: never use the 2nd __launch_bounds__ arg (spill cliff r2/r4).
// ===========================================================================

__device__ __forceinline__ short f2bfs(float f) {
    union { __bf16 b; short s; } c; c.b = (__bf16)f; return c.s;
}
__device__ __forceinline__ unsigned f2bfbits(float f) {
    union { __bf16 b; unsigned short u; } c; c.b = (__bf16)f; return (unsigned)c.u;
}
__device__ __forceinline__ float bfbits2f(unsigned bits32) {
    union { unsigned u; float f; } c; c.u = bits32; return c.f;
}

// ---- compose A_g / B_t (r12/r14 version: 64 blocks x 64 threads) -----------
__global__ __launch_bounds__(64) void compose_pack(const float* __restrict__ Ws,
                                                   short* __restrict__ wf) {
    __shared__ float M[32 * 32];
    const int b = blockIdx.x;
    const int tid = threadIdx.x;
    const bool isB = b >= 32;
    const int grp = isB ? b - 32 : b;

    for (int s = tid; s < 1024; s += 64) M[s] = ((s >> 5) == (s & 31)) ? 1.f : 0.f;
    __syncthreads();

    for (int il = 0; il < 5; ++il) {
        #pragma unroll
        for (int s = 0; s < 8; ++s) {
            int task = tid + s * 64;        // 512 tasks: pl(16) x row(32), disjoint
            int pl = task >> 5;
            int r  = task & 31;
            int lo = ((pl >> il) << (il + 1)) | (pl & ((1 << il) - 1));
            int hi = lo + (1 << il);
            int wi = isB ? ((5 + il) * 512 + pl * 32 + grp)
                         : (il * 512 + grp * 16 + pl);
            const float* W = Ws + (size_t)wi * 4;
            float w00 = W[0], w01 = W[1], w10 = W[2], w11 = W[3];
            float u = M[r * 32 + lo], v = M[r * 32 + hi];
            M[r * 32 + lo] = u * w00 + v * w10;
            M[r * 32 + hi] = u * w01 + v * w11;
        }
        __syncthreads();
    }

    // fragment: lane supplies M[k=(tid>>4)*8+e][nh*16 + (tid&15)]
    const int q = tid >> 4, lr = tid & 15;
    #pragma unroll
    for (int nh = 0; nh < 2; ++nh) {
        bf16x8 fr;
        #pragma unroll
        for (int e = 0; e < 8; ++e)
            fr[e] = f2bfs(M[(q * 8 + e) * 32 + nh * 16 + lr]);
        size_t idx = (size_t)(isB ? 4096 : 0) + ((size_t)grp * 2 + nh) * 64 + tid;
        ((bf16x8*)wf)[idx] = fr;
    }
}

// ---- main fused kernel: 16 rows per block, ONE wave ------------------------
__global__ __launch_bounds__(64) void bfly_mfma(
    const float* __restrict__ x,
    const short* __restrict__ wf1,
    const short* __restrict__ wf2,
    float* __restrict__ out)
{
    __shared__ char zt[32 * 1024];
    const int l = threadIdx.x;           // 0..63
    const int q = l >> 4, lr = l & 15;
    const int row0 = blockIdx.x * ROWS_PER_TILE;

    const f32x4 zacc = {0.f, 0.f, 0.f, 0.f};
    const float* xrow = x + (size_t)(row0 + lr) * DIM;

    // ---- layer 1: all 32 groups, chunks of 8; plain x loads (L1 pairs) ----
    #pragma unroll
    for (int gc = 0; gc < 4; ++gc) {
        bf16x8 zfr[2][4];
        #pragma unroll
        for (int gi = 0; gi < 8; ++gi) {
            const int g = gc * 8 + gi;
            const f32x4* xp = (const f32x4*)(xrow + g * 32 + q * 8);
            f32x4 xa = xp[0], xb = xp[1];
            bf16x8 af;
            af[0] = f2bfs(xa[0]); af[1] = f2bfs(xa[1]);
            af[2] = f2bfs(xa[2]); af[3] = f2bfs(xa[3]);
            af[4] = f2bfs(xb[0]); af[5] = f2bfs(xb[1]);
            af[6] = f2bfs(xb[2]); af[7] = f2bfs(xb[3]);
            bf16x8 b0 = ((const bf16x8*)wf1)[(g * 2 + 0) * 64 + l];
            bf16x8 b1 = ((const bf16x8*)wf1)[(g * 2 + 1) * 64 + l];
            f32x4 c0 = __builtin_amdgcn_mfma_f32_16x16x32_bf16(b0, af, zacc, 0, 0, 0);
            f32x4 c1 = __builtin_amdgcn_mfma_f32_16x16x32_bf16(b1, af, zacc, 0, 0, 0);
            #pragma unroll
            for (int i = 0; i < 4; ++i) {
                zfr[0][i][gi] = f2bfs(c0[i]);
                zfr[1][i][gi] = f2bfs(c1[i]);
            }
        }
        #pragma unroll
        for (int nh = 0; nh < 2; ++nh) {
            #pragma unroll
            for (int i = 0; i < 4; ++i) {
                int c = nh * 16 + q * 4 + i;
                unsigned U = (unsigned)(c * 64 + lr * 4 + gc);
                U ^= (U >> 8) & 3;
                *(bf16x8*)(zt + U * 16) = zfr[nh][i];
            }
        }
    }
    __syncthreads();   // 1-wave barrier: drain zt writes for cross-lane reads

    // ---- layer 2 (swapped): t-loop; y accumulated in regs ----
    f32x4 y[2][4][8];
    #pragma unroll
    for (int t = 0; t < 32; ++t) {
        unsigned U = (unsigned)(t * 64 + lr * 4 + q);
        U ^= (U >> 8) & 3;
        bf16x8 a2 = *(const bf16x8*)(zt + U * 16);
        bf16x8 b0 = ((const bf16x8*)wf2)[(t * 2 + 0) * 64 + l];
        bf16x8 b1 = ((const bf16x8*)wf2)[(t * 2 + 1) * 64 + l];
        f32x4 o0 = __builtin_amdgcn_mfma_f32_16x16x32_bf16(b0, a2, zacc, 0, 0, 0);
        f32x4 o1 = __builtin_amdgcn_mfma_f32_16x16x32_bf16(b1, a2, zacc, 0, 0, 0);
        #pragma unroll
        for (int i = 0; i < 4; ++i) {
            y[0][i][t >> 2][t & 3] = o0[i];
            y[1][i][t >> 2][t & 3] = o1[i];
        }
    }
    __syncthreads();   // all zt reads done before reuse as y staging

    // ---- stage y (bf16) into zt: unit V = lr*128 + c*4 + tc ----
    #pragma unroll
    for (int nh = 0; nh < 2; ++nh) {
        #pragma unroll
        for (int i = 0; i < 4; ++i) {
            int c = nh * 16 + q * 4 + i;
            #pragma unroll
            for (int tc = 0; tc < 4; ++tc) {
                f32x4 ya = y[nh][i][tc * 2], yb = y[nh][i][tc * 2 + 1];
                u32x4 pk;
                pk[0] = f2bfbits(ya[0]) | (f2bfbits(ya[1]) << 16);
                pk[1] = f2bfbits(ya[2]) | (f2bfbits(ya[3]) << 16);
                pk[2] = f2bfbits(yb[0]) | (f2bfbits(yb[1]) << 16);
                pk[3] = f2bfbits(yb[2]) | (f2bfbits(yb[3]) << 16);
                unsigned V = (unsigned)(lr * 128 + c * 4 + tc);
                V ^= (V >> 7) & 7;
                *(u32x4*)(zt + V * 16) = pk;
            }
        }
    }
    __syncthreads();   // drain staging for cross-lane final reads

    // ---- final stores: per instruction 16 rows x one dense 128B line ----
    const int srow = l >> 2;    // 0..15
    const int scb  = l & 3;     // 0..3
    float* orow = out + (size_t)(row0 + srow) * DIM;
    #pragma unroll
    for (int j = 0; j < 32; ++j) {
        unsigned V = (unsigned)(srow * 128 + j * 4 + scb);
        V ^= (V >> 7) & 7;
        u32x4 pk = *(const u32x4*)(zt + V * 16);
        f32x4 v0, v1;
        v0[0] = bfbits2f(pk[0] << 16); v0[1] = bfbits2f(pk[0] & 0xffff0000u);
        v0[2] = bfbits2f(pk[1] << 16); v0[3] = bfbits2f(pk[1] & 0xffff0000u);
        v1[0] = bfbits2f(pk[2] << 16); v1[1] = bfbits2f(pk[2] & 0xffff0000u);
        v1[2] = bfbits2f(pk[3] << 16); v1[3] = bfbits2f(pk[3] & 0xffff0000u);
        float* dst = orow + j * 32 + scb * 8;
        __builtin_nontemporal_store(v0, (f32x4*)dst);
        __builtin_nontemporal_store(v1, (f32x4*)dst + 1);
    }
}

// ---- fallback (ws too small / odd rows): r6-style shuffle butterfly --------
__global__ __launch_bounds__(256) void butterfly_fallback(
    const float* __restrict__ x, const float* __restrict__ Ws,
    float* __restrict__ out, int rows)
{
    const int lane = threadIdx.x & 63;
    const int wave = threadIdx.x >> 6;
    const int row0 = (blockIdx.x * 4 + wave) * 2;
    const float4* __restrict__ Wm = (const float4*)Ws;
    float d[2][16];
    #pragma unroll
    for (int r = 0; r < 2; ++r) {
        int row = row0 + r;
        if (row < rows) {
            const f32x4* src = (const f32x4*)(x + (size_t)row * DIM);
            #pragma unroll
            for (int qq = 0; qq < 4; ++qq) {
                f32x4 v = src[qq * 64 + lane];
                d[r][qq*4+0]=v[0]; d[r][qq*4+1]=v[1]; d[r][qq*4+2]=v[2]; d[r][qq*4+3]=v[3];
            }
        } else { for (int e = 0; e < 16; ++e) d[r][e] = 0.f; }
    }
    #pragma unroll
    for (int qq = 0; qq < 4; ++qq) {
        int base = qq*128 + lane*2;
        float4 m0 = Wm[base], m1 = Wm[base+1];
        #pragma unroll
        for (int r = 0; r < 2; ++r) {
            int e = qq*4; float u,v;
            u=d[r][e+0]; v=d[r][e+1]; d[r][e+0]=u*m0.x+v*m0.z; d[r][e+1]=u*m0.y+v*m0.w;
            u=d[r][e+2]; v=d[r][e+3]; d[r][e+2]=u*m1.x+v*m1.z; d[r][e+3]=u*m1.y+v*m1.w;
        }
    }
    #pragma unroll
    for (int qq = 0; qq < 4; ++qq) {
        int base = 512 + qq*128 + lane*2;
        float4 m0 = Wm[base], m1 = Wm[base+1];
        #pragma unroll
        for (int r = 0; r < 2; ++r) {
            int e = qq*4; float u,v;
            u=d[r][e+0]; v=d[r][e+2]; d[r][e+0]=u*m0.x+v*m0.z; d[r][e+2]=u*m0.y+v*m0.w;
            u=d[r][e+1]; v=d[r][e+3]; d[r][e+1]=u*m1.x+v*m1.z; d[r][e+3]=u*m1.y+v*m1.w;
        }
    }
    #pragma unroll
    for (int i = 2; i < 8; ++i) {
        const int m = 1 << (i - 2);
        #pragma unroll
        for (int qq = 0; qq < 4; ++qq) {
            const int a = (lane >> (i - 2)) & 1;
            int P0 = (((qq*64 + lane) >> (i-1)) << i) | ((lane & (m-1)) << 2);
            int base = i*512 + P0;
            float4 M0 = Wm[base+0], M1 = Wm[base+1], M2 = Wm[base+2], M3 = Wm[base+3];
            float wA0 = a ? M0.w : M0.x, wB0 = a ? M0.y : M0.z;
            float wA1 = a ? M1.w : M1.x, wB1 = a ? M1.y : M1.z;
            float wA2 = a ? M2.w : M2.x, wB2 = a ? M2.y : M2.z;
            float wA3 = a ? M3.w : M3.x, wB3 = a ? M3.y : M3.z;
            #pragma unroll
            for (int r = 0; r < 2; ++r) {
                int e = qq*4;
                float o0=__shfl_xor(d[r][e+0],m), o1=__shfl_xor(d[r][e+1],m);
                float o2=__shfl_xor(d[r][e+2],m), o3=__shfl_xor(d[r][e+3],m);
                d[r][e+0]=d[r][e+0]*wA0+o0*wB0; d[r][e+1]=d[r][e+1]*wA1+o1*wB1;
                d[r][e+2]=d[r][e+2]*wA2+o2*wB2; d[r][e+3]=d[r][e+3]*wA3+o3*wB3;
            }
        }
    }
    #pragma unroll
    for (int qp = 0; qp < 2; ++qp) {
        int base = 8*512 + qp*256 + lane*4;
        float4 M0 = Wm[base+0], M1 = Wm[base+1], M2 = Wm[base+2], M3 = Wm[base+3];
        #pragma unroll
        for (int r = 0; r < 2; ++r) {
            int eu=(2*qp)*4, ev=(2*qp+1)*4; float u,v;
            u=d[r][eu+0]; v=d[r][ev+0]; d[r][eu+0]=u*M0.x+v*M0.z; d[r][ev+0]=u*M0.y+v*M0.w;
            u=d[r][eu+1]; v=d[r][ev+1]; d[r][eu+1]=u*M1.x+v*M1.z; d[r][ev+1]=u*M1.y+v*M1.w;
            u=d[r][eu+2]; v=d[r][ev+2]; d[r][eu+2]=u*M2.x+v*M2.z; d[r][ev+2]=u*M2.y+v*M2.w;
            u=d[r][eu+3]; v=d[r][ev+3]; d[r][eu+3]=u*M3.x+v*M3.z; d[r][ev+3]=u*M3.y+v*M3.w;
        }
    }
    #pragma unroll
    for (int qp = 0; qp < 2; ++qp) {
        int base = 9*512 + qp*256 + lane*4;
        float4 M0 = Wm[base+0], M1 = Wm[base+1], M2 = Wm[base+2], M3 = Wm[base+3];
        #pragma unroll
        for (int r = 0; r < 2; ++r) {
            int eu=qp*4, ev=(qp+2)*4; float u,v;
            u=d[r][eu+0]; v=d[r][ev+0]; d[r][eu+0]=u*M0.x+v*M0.z; d[r][ev+0]=u*M0.y+v*M0.w;
            u=d[r][eu+1]; v=d[r][ev+1]; d[r][eu+1]=u*M1.x+v*M1.z; d[r][ev+1]=u*M1.y+v*M1.w;
            u=d[r][eu+2]; v=d[r][ev+2]; d[r][eu+2]=u*M2.x+v*M2.z; d[r][ev+2]=u*M2.y+v*M2.w;
            u=d[r][eu+3]; v=d[r][ev+3]; d[r][eu+3]=u*M3.x+v*M3.z; d[r][ev+3]=u*M3.y+v*M3.w;
        }
    }
    #pragma unroll
    for (int r = 0; r < 2; ++r) {
        int row = row0 + r;
        if (row < rows) {
            f32x4* dst = (f32x4*)(out + (size_t)row * DIM);
            #pragma unroll
            for (int qq = 0; qq < 4; ++qq) {
                f32x4 v = { d[r][qq*4+0], d[r][qq*4+1], d[r][qq*4+2], d[r][qq*4+3] };
                dst[qq * 64 + lane] = v;
            }
        }
    }
}

extern "C" void kernel_launch(void* const* d_in, const int* in_sizes, int n_in,
                              void* d_out, int out_size, void* d_ws, size_t ws_size,
                              hipStream_t stream) {
    const float* x  = (const float*)d_in[0];
    const float* Ws = (const float*)d_in[1];
    float* out = (float*)d_out;
    int rows = in_sizes[0] / DIM;

    if (ws_size >= (size_t)WF_BYTES && (rows % ROWS_PER_TILE) == 0) {
        short* wf1 = (short*)d_ws;
        short* wf2 = (short*)d_ws + 32768;   // +64KB
        compose_pack<<<64, 64, 0, stream>>>(Ws, (short*)d_ws);
        bfly_mfma<<<rows / ROWS_PER_TILE, 64, 0, stream>>>(x, wf1, wf2, out);
    } else {
        int grid = (rows + 7) / 8;
        butterfly_fallback<<<grid, 256, 0, stream>>>(x, Ws, out, rows);
    }
}

// Round 16
// 47.840 us; speedup vs baseline: 1.2890x; 1.2890x over previous
//
#include <hip/hip_runtime.h>

#define DIM 1024
#define ROWS_PER_TILE 16

typedef float  f32x4  __attribute__((ext_vector_type(4)));
typedef short  bf16x8 __attribute__((ext_vector_type(8)));
typedef unsigned int u32x2 __attribute__((ext_vector_type(2)));
typedef unsigned int u32x4 __attribute__((ext_vector_type(4)));

#define WF_BYTES (2 * 32 * 2 * 64 * 16)   // wf1 (64KB) + wf2 (64KB) in d_ws

// ===========================================================================
// r16 = r12 (best measured MFMA variant, bfly <40us, absmax 8.0) with the two
// measured serial-latency chains removed:
//  - compose_pack: W prefetched to LDS in ONE in-flight batch (was 40 serial
//    L2 loads ~6us).
//  - bfly: 16 x-loads + 16 wf1 frag loads hoisted to registers BEFORE the
//    layer-1 loop (32 loads in flight); wf2 frag loads issued before barrier-1
//    (complete during the barrier's vmcnt drain).
// All layouts/swizzles/algebra byte-identical to r12 (verified).
// NOTE: never use the 2nd __launch_bounds__ arg (spill cliff r2/r4).
// ===========================================================================

__device__ __forceinline__ short f2bfs(float f) {
    union { __bf16 b; short s; } c; c.b = (__bf16)f; return c.s;
}
__device__ __forceinline__ unsigned f2bfbits(float f) {
    union { __bf16 b; unsigned short u; } c; c.b = (__bf16)f; return (unsigned)c.u;
}
__device__ __forceinline__ float bfbits2f(unsigned bits32) {
    union { unsigned u; float f; } c; c.u = bits32; return c.f;
}

// ---- compose A_g / B_t; 64 blocks x 64 threads; W prefetched to LDS --------
__global__ __launch_bounds__(64) void compose_pack(const float* __restrict__ Ws,
                                                   short* __restrict__ wf) {
    __shared__ float M[32 * 32];
    __shared__ float WL[80 * 4];          // [il*16+pl][4]
    const int b = blockIdx.x;
    const int tid = threadIdx.x;
    const bool isB = b >= 32;
    const int grp = isB ? b - 32 : b;

    // prefetch all 80 W matrices (float4 each) — all loads in flight at once
    {
        const float4* W4 = (const float4*)Ws;
        #pragma unroll
        for (int s = 0; s < 2; ++s) {
            int t = tid + s * 64;
            if (t < 80) {
                int il = t >> 4, pl = t & 15;
                int wi = isB ? ((5 + il) * 512 + pl * 32 + grp)
                             : (il * 512 + grp * 16 + pl);
                float4 wv = W4[wi];
                WL[t * 4 + 0] = wv.x; WL[t * 4 + 1] = wv.y;
                WL[t * 4 + 2] = wv.z; WL[t * 4 + 3] = wv.w;
            }
        }
    }
    for (int s = tid; s < 1024; s += 64) M[s] = ((s >> 5) == (s & 31)) ? 1.f : 0.f;
    __syncthreads();

    for (int il = 0; il < 5; ++il) {
        #pragma unroll
        for (int s = 0; s < 8; ++s) {
            int task = tid + s * 64;        // 512 tasks: pl(16) x row(32), disjoint
            int pl = task >> 5;
            int r  = task & 31;
            int lo = ((pl >> il) << (il + 1)) | (pl & ((1 << il) - 1));
            int hi = lo + (1 << il);
            const float* W = &WL[(il * 16 + pl) * 4];
            float w00 = W[0], w01 = W[1], w10 = W[2], w11 = W[3];
            float u = M[r * 32 + lo], v = M[r * 32 + hi];
            M[r * 32 + lo] = u * w00 + v * w10;
            M[r * 32 + hi] = u * w01 + v * w11;
        }
        __syncthreads();
    }

    // fragment: lane supplies M[k=(tid>>4)*8+e][nh*16 + (tid&15)]
    const int q = tid >> 4, lr = tid & 15;
    #pragma unroll
    for (int nh = 0; nh < 2; ++nh) {
        bf16x8 fr;
        #pragma unroll
        for (int e = 0; e < 8; ++e)
            fr[e] = f2bfs(M[(q * 8 + e) * 32 + nh * 16 + lr]);
        size_t idx = (size_t)(isB ? 4096 : 0) + ((size_t)grp * 2 + nh) * 64 + tid;
        ((bf16x8*)wf)[idx] = fr;
    }
}

// ---- main fused kernel: 16 rows per block, 4 waves (r12 structure) ---------
__global__ __launch_bounds__(256) void bfly_mfma(
    const float* __restrict__ x,
    const short* __restrict__ wf1,
    const short* __restrict__ wf2,
    float* __restrict__ out)
{
    __shared__ char zt[32 * 1024];   // layer1->2 transpose, then y bf16 staging
    const int tid = threadIdx.x;
    const int w = tid >> 6;
    const int l = tid & 63;
    const int q = l >> 4, lr = l & 15;
    const int row0 = blockIdx.x * ROWS_PER_TILE;

    const f32x4 zacc = {0.f, 0.f, 0.f, 0.f};

    // ---- hoist: 16 x loads + 16 wf1 frag loads, ALL in flight ----
    const float* xrow = x + (size_t)(row0 + lr) * DIM;
    f32x4 xv[16];
    #pragma unroll
    for (int gi = 0; gi < 8; ++gi) {
        const f32x4* xp = (const f32x4*)(xrow + (w * 8 + gi) * 32 + q * 8);
        xv[2 * gi]     = __builtin_nontemporal_load(xp);
        xv[2 * gi + 1] = __builtin_nontemporal_load(xp + 1);
    }
    bf16x8 bfr1[16];
    #pragma unroll
    for (int gi = 0; gi < 8; ++gi) {
        const int g = w * 8 + gi;
        bfr1[2 * gi]     = ((const bf16x8*)wf1)[(g * 2 + 0) * 64 + l];
        bfr1[2 * gi + 1] = ((const bf16x8*)wf1)[(g * 2 + 1) * 64 + l];
    }

    // ---- layer 1: A = x frag, B = wf1 frag (r12-verified) ----
    #pragma unroll
    for (int gi = 0; gi < 8; ++gi) {
        const int g = w * 8 + gi;
        f32x4 xa = xv[2 * gi], xb = xv[2 * gi + 1];
        bf16x8 af;
        af[0] = f2bfs(xa[0]); af[1] = f2bfs(xa[1]);
        af[2] = f2bfs(xa[2]); af[3] = f2bfs(xa[3]);
        af[4] = f2bfs(xb[0]); af[5] = f2bfs(xb[1]);
        af[6] = f2bfs(xb[2]); af[7] = f2bfs(xb[3]);
        f32x4 c0 = __builtin_amdgcn_mfma_f32_16x16x32_bf16(af, bfr1[2*gi],   zacc, 0, 0, 0);
        f32x4 c1 = __builtin_amdgcn_mfma_f32_16x16x32_bf16(af, bfr1[2*gi+1], zacc, 0, 0, 0);
        #pragma unroll
        for (int nh = 0; nh < 2; ++nh) {
            f32x4 cc = nh ? c1 : c0;
            int c = nh * 16 + lr;                 // z col within group
            unsigned lo = f2bfbits(cc[0]) | (f2bfbits(cc[1]) << 16);
            unsigned hi = f2bfbits(cc[2]) | (f2bfbits(cc[3]) << 16);
            int byteoff = (c * 1024 + g * 32 + q * 8) ^ ((c & 15) << 3);
            u32x2 pk = {lo, hi};
            *(u32x2*)(zt + byteoff) = pk;
        }
    }

    // ---- issue wf2 frag loads BEFORE the barrier (complete during drain) ----
    bf16x8 bfr2[16];
    #pragma unroll
    for (int hh = 0; hh < 8; ++hh) {
        const int h = w * 8 + hh;
        bfr2[2 * hh]     = ((const bf16x8*)wf2)[(h * 2 + 0) * 64 + l];
        bfr2[2 * hh + 1] = ((const bf16x8*)wf2)[(h * 2 + 1) * 64 + l];
    }
    __syncthreads();

    // ---- layer 2 (swapped operands, r12-verified): A = wf2 frag, B = z frag --
    f32x4 o[2][8];
    #pragma unroll
    for (int hh = 0; hh < 8; ++hh) {
        const int h = w * 8 + hh;
        bf16x8 a2;
        #pragma unroll
        for (int e = 0; e < 8; ++e) {
            int byteoff = (h * 1024 + (q * 8 + e) * 32 + lr * 2) ^ ((h & 15) << 3);
            union { unsigned short u; short s; } cv;
            cv.u = *(const unsigned short*)(zt + byteoff);
            a2[e] = cv.s;
        }
        o[0][hh] = __builtin_amdgcn_mfma_f32_16x16x32_bf16(bfr2[2*hh],   a2, zacc, 0, 0, 0);
        o[1][hh] = __builtin_amdgcn_mfma_f32_16x16x32_bf16(bfr2[2*hh+1], a2, zacc, 0, 0, 0);
    }
    __syncthreads();   // all zt reads done before reuse as y-staging

    // ---- stage y into LDS as bf16 [row][col], swizzled 16B units (r12) ----
    #pragma unroll
    for (int nh = 0; nh < 2; ++nh) {
        #pragma unroll
        for (int i = 0; i < 4; ++i) {
            unsigned p0 = f2bfbits(o[nh][0][i]) | (f2bfbits(o[nh][1][i]) << 16);
            unsigned p1 = f2bfbits(o[nh][2][i]) | (f2bfbits(o[nh][3][i]) << 16);
            unsigned p2 = f2bfbits(o[nh][4][i]) | (f2bfbits(o[nh][5][i]) << 16);
            unsigned p3 = f2bfbits(o[nh][6][i]) | (f2bfbits(o[nh][7][i]) << 16);
            int colb = (nh * 16 + q * 4 + i) * 32 + w * 8;
            int u = lr * 128 + (colb >> 3);       // 16-B unit index
            u ^= (u >> 7) & 7;                    // bank-balance (involution)
            u32x4 pk = {p0, p1, p2, p3};
            *(u32x4*)(zt + u * 16) = pk;
        }
    }
    __syncthreads();

    // ---- coalesced f32 stores: thread t -> row t>>4, 8x (16B LDS -> 32B out) --
    const int trow = tid >> 4;
    const int tcb  = tid & 15;
    float* orow = out + (size_t)(row0 + trow) * DIM;
    #pragma unroll
    for (int j = 0; j < 8; ++j) {
        int ucol = j * 16 + tcb;                  // 0..127
        int u = trow * 128 + ucol;
        u ^= (u >> 7) & 7;
        u32x4 pk = *(const u32x4*)(zt + u * 16);
        f32x4 v0, v1;
        v0[0] = bfbits2f(pk[0] << 16); v0[1] = bfbits2f(pk[0] & 0xffff0000u);
        v0[2] = bfbits2f(pk[1] << 16); v0[3] = bfbits2f(pk[1] & 0xffff0000u);
        v1[0] = bfbits2f(pk[2] << 16); v1[1] = bfbits2f(pk[2] & 0xffff0000u);
        v1[2] = bfbits2f(pk[3] << 16); v1[3] = bfbits2f(pk[3] & 0xffff0000u);
        float* dst = orow + ucol * 8;
        *(f32x4*)dst = v0;
        *((f32x4*)dst + 1) = v1;
    }
}

// ---- fallback (ws too small / odd rows): r6-style shuffle butterfly --------
__global__ __launch_bounds__(256) void butterfly_fallback(
    const float* __restrict__ x, const float* __restrict__ Ws,
    float* __restrict__ out, int rows)
{
    const int lane = threadIdx.x & 63;
    const int wave = threadIdx.x >> 6;
    const int row0 = (blockIdx.x * 4 + wave) * 2;
    const float4* __restrict__ Wm = (const float4*)Ws;
    float d[2][16];
    #pragma unroll
    for (int r = 0; r < 2; ++r) {
        int row = row0 + r;
        if (row < rows) {
            const f32x4* src = (const f32x4*)(x + (size_t)row * DIM);
            #pragma unroll
            for (int qq = 0; qq < 4; ++qq) {
                f32x4 v = src[qq * 64 + lane];
                d[r][qq*4+0]=v[0]; d[r][qq*4+1]=v[1]; d[r][qq*4+2]=v[2]; d[r][qq*4+3]=v[3];
            }
        } else { for (int e = 0; e < 16; ++e) d[r][e] = 0.f; }
    }
    #pragma unroll
    for (int qq = 0; qq < 4; ++qq) {
        int base = qq*128 + lane*2;
        float4 m0 = Wm[base], m1 = Wm[base+1];
        #pragma unroll
        for (int r = 0; r < 2; ++r) {
            int e = qq*4; float u,v;
            u=d[r][e+0]; v=d[r][e+1]; d[r][e+0]=u*m0.x+v*m0.z; d[r][e+1]=u*m0.y+v*m0.w;
            u=d[r][e+2]; v=d[r][e+3]; d[r][e+2]=u*m1.x+v*m1.z; d[r][e+3]=u*m1.y+v*m1.w;
        }
    }
    #pragma unroll
    for (int qq = 0; qq < 4; ++qq) {
        int base = 512 + qq*128 + lane*2;
        float4 m0 = Wm[base], m1 = Wm[base+1];
        #pragma unroll
        for (int r = 0; r < 2; ++r) {
            int e = qq*4; float u,v;
            u=d[r][e+0]; v=d[r][e+2]; d[r][e+0]=u*m0.x+v*m0.z; d[r][e+2]=u*m0.y+v*m0.w;
            u=d[r][e+1]; v=d[r][e+3]; d[r][e+1]=u*m1.x+v*m1.z; d[r][e+3]=u*m1.y+v*m1.w;
        }
    }
    #pragma unroll
    for (int i = 2; i < 8; ++i) {
        const int m = 1 << (i - 2);
        #pragma unroll
        for (int qq = 0; qq < 4; ++qq) {
            const int a = (lane >> (i - 2)) & 1;
            int P0 = (((qq*64 + lane) >> (i-1)) << i) | ((lane & (m-1)) << 2);
            int base = i*512 + P0;
            float4 M0 = Wm[base+0], M1 = Wm[base+1], M2 = Wm[base+2], M3 = Wm[base+3];
            float wA0 = a ? M0.w : M0.x, wB0 = a ? M0.y : M0.z;
            float wA1 = a ? M1.w : M1.x, wB1 = a ? M1.y : M1.z;
            float wA2 = a ? M2.w : M2.x, wB2 = a ? M2.y : M2.z;
            float wA3 = a ? M3.w : M3.x, wB3 = a ? M3.y : M3.z;
            #pragma unroll
            for (int r = 0; r < 2; ++r) {
                int e = qq*4;
                float o0=__shfl_xor(d[r][e+0],m), o1=__shfl_xor(d[r][e+1],m);
                float o2=__shfl_xor(d[r][e+2],m), o3=__shfl_xor(d[r][e+3],m);
                d[r][e+0]=d[r][e+0]*wA0+o0*wB0; d[r][e+1]=d[r][e+1]*wA1+o1*wB1;
                d[r][e+2]=d[r][e+2]*wA2+o2*wB2; d[r][e+3]=d[r][e+3]*wA3+o3*wB3;
            }
        }
    }
    #pragma unroll
    for (int qp = 0; qp < 2; ++qp) {
        int base = 8*512 + qp*256 + lane*4;
        float4 M0 = Wm[base+0], M1 = Wm[base+1], M2 = Wm[base+2], M3 = Wm[base+3];
        #pragma unroll
        for (int r = 0; r < 2; ++r) {
            int eu=(2*qp)*4, ev=(2*qp+1)*4; float u,v;
            u=d[r][eu+0]; v=d[r][ev+0]; d[r][eu+0]=u*M0.x+v*M0.z; d[r][ev+0]=u*M0.y+v*M0.w;
            u=d[r][eu+1]; v=d[r][ev+1]; d[r][eu+1]=u*M1.x+v*M1.z; d[r][ev+1]=u*M1.y+v*M1.w;
            u=d[r][eu+2]; v=d[r][ev+2]; d[r][eu+2]=u*M2.x+v*M2.z; d[r][ev+2]=u*M2.y+v*M2.w;
            u=d[r][eu+3]; v=d[r][ev+3]; d[r][eu+3]=u*M3.x+v*M3.z; d[r][ev+3]=u*M3.y+v*M3.w;
        }
    }
    #pragma unroll
    for (int qp = 0; qp < 2; ++qp) {
        int base = 9*512 + qp*256 + lane*4;
        float4 M0 = Wm[base+0], M1 = Wm[base+1], M2 = Wm[base+2], M3 = Wm[base+3];
        #pragma unroll
        for (int r = 0; r < 2; ++r) {
            int eu=qp*4, ev=(qp+2)*4; float u,v;
            u=d[r][eu+0]; v=d[r][ev+0]; d[r][eu+0]=u*M0.x+v*M0.z; d[r][ev+0]=u*M0.y+v*M0.w;
            u=d[r][eu+1]; v=d[r][ev+1]; d[r][eu+1]=u*M1.x+v*M1.z; d[r][ev+1]=u*M1.y+v*M1.w;
            u=d[r][eu+2]; v=d[r][ev+2]; d[r][eu+2]=u*M2.x+v*M2.z; d[r][ev+2]=u*M2.y+v*M2.w;
            u=d[r][eu+3]; v=d[r][ev+3]; d[r][eu+3]=u*M3.x+v*M3.z; d[r][ev+3]=u*M3.y+v*M3.w;
        }
    }
    #pragma unroll
    for (int r = 0; r < 2; ++r) {
        int row = row0 + r;
        if (row < rows) {
            f32x4* dst = (f32x4*)(out + (size_t)row * DIM);
            #pragma unroll
            for (int qq = 0; qq < 4; ++qq) {
                f32x4 v = { d[r][qq*4+0], d[r][qq*4+1], d[r][qq*4+2], d[r][qq*4+3] };
                dst[qq * 64 + lane] = v;
            }
        }
    }
}

extern "C" void kernel_launch(void* const* d_in, const int* in_sizes, int n_in,
                              void* d_out, int out_size, void* d_ws, size_t ws_size,
                              hipStream_t stream) {
    const float* x  = (const float*)d_in[0];
    const float* Ws = (const float*)d_in[1];
    float* out = (float*)d_out;
    int rows = in_sizes[0] / DIM;

    if (ws_size >= (size_t)WF_BYTES && (rows % ROWS_PER_TILE) == 0) {
        short* wf1 = (short*)d_ws;
        short* wf2 = (short*)d_ws + 32768;   // +64KB
        compose_pack<<<64, 64, 0, stream>>>(Ws, (short*)d_ws);
        bfly_mfma<<<rows / ROWS_PER_TILE, 256, 0, stream>>>(x, wf1, wf2, out);
    } else {
        int grid = (rows + 7) / 8;
        butterfly_fallback<<<grid, 256, 0, stream>>>(x, Ws, out, rows);
    }
}